// Round 22
// baseline (748.836 us; speedup 1.0000x reference)
//
#include <hip/hip_runtime.h>
#include <hip/hip_bf16.h>
#include <cstdint>
#include <cstddef>

// Problem constants
#define B_ 64
#define S_ 4096
#define D_ 256
#define BM 64                   // rows per block (4 waves x 16 rows)
#define BK 32                   // k-step
#define NBLK (B_ * S_ / BM)     // 4096
#define BLKS_PER_B (S_ / BM)    // 64

typedef __attribute__((ext_vector_type(8))) short short8;
typedef __attribute__((ext_vector_type(4))) float f32x4;
typedef __attribute__((ext_vector_type(4))) float f4;

__device__ __forceinline__ short f2bf(float f) {
  union { float f; uint32_t u; } v; v.f = f;
  uint32_t r = v.u + 0x7FFFu + ((v.u >> 16) & 1u);   // RNE
  return (short)(r >> 16);
}

__device__ __forceinline__ short f2bf_i(float f) {
  // compiler-visible RNE convert (no inline asm; R17/R18/R19/R21-proven)
  union { __hip_bfloat16 b; short s; } v;
  v.b = __float2bfloat16(f);
  return v.s;
}

__device__ __forceinline__ float fast_tanh(float z) {
  // tanh(z) = 1 - 2*rcp(e^{2z}+1); overflow-safe; PASSED R4/5/6/14/17/18/19/21
  return 1.0f - 2.0f * __builtin_amdgcn_rcpf(__expf(2.0f * z) + 1.0f);
}

__device__ __forceinline__ void gload_lds16(const short* g, short* l) {
  __builtin_amdgcn_global_load_lds(
      (const __attribute__((address_space(1))) int*)(g),
      (__attribute__((address_space(3))) int*)(l), 16, 0, 0);
}

// Kernel 0: FRAG-PACKED Wt (R18 layout) + zero the per-batch completion
// counters (64 blocks = 64 batches; runs before k_scores on the stream).
__global__ void k_pack(const float* __restrict__ W, short* __restrict__ wt,
                       int* __restrict__ ws_cnt) {
  if (threadIdx.x == 0) ws_cnt[blockIdx.x] = 0;
  int idx = blockIdx.x * 1024 + threadIdx.x;   // 65536 elements
  int n = idx & 255, k = idx >> 8;             // coalesced read of row k
  int out = (k >> 5) * 8192 +
            (((n >> 4) * 64 + ((k >> 3) & 3) * 16 + (n & 15)) << 3) + (k & 7);
  wt[out] = f2bf(W[k * 256 + n]);
}

// ---- k_scores helper macros (R19/R21-proven pipeline) -----------------------
#define WAITV(N) asm volatile("s_waitcnt vmcnt(" #N ")" ::: "memory")
#define FENCE()  asm volatile("" ::: "memory")

// Stage B k-step KC into lsB[BUF]: 16 KB, 4 x global_load_lds(16B) per thread.
#define STAGE(BUF, KC)                                                        \
  {                                                                           \
    _Pragma("unroll")                                                         \
    for (int i_ = 0; i_ < 4; ++i_) {                                          \
      int c_ = i_ * 256 + tid;                                                \
      gload_lds16(wt + (KC) * 8192 + c_ * 8, &lsB[BUF][c_ * 8]);              \
    }                                                                         \
  }

// One pipelined K-step (R21 verbatim): stage(K+1), issue A(K+2), counted
// vmcnt, barriers, cvt A(K), 16 MFMAs (lane-linear conflict-free B reads).
#define ITER(KC, VM, SCA, SCB, SLA, SLB, DOSTAGE, DOLOAD)                     \
  {                                                                           \
    if (DOSTAGE) STAGE(((KC) + 1) & 1, (KC) + 1);                             \
    if (DOLOAD) {                                                             \
      SLA = *(const f4*)(xrow + ((KC) + 2) * 32);                             \
      SLB = *(const f4*)(xrow + ((KC) + 2) * 32 + 4);                         \
    }                                                                         \
    WAITV(VM);                                                                \
    asm volatile("s_waitcnt lgkmcnt(0)" ::: "memory");                        \
    __builtin_amdgcn_sched_barrier(0);                                        \
    __builtin_amdgcn_s_barrier();                                             \
    FENCE();                                                                  \
    short8 fr_;                                                               \
    fr_[0]=f2bf_i(SCA[0]); fr_[1]=f2bf_i(SCA[1]); fr_[2]=f2bf_i(SCA[2]); fr_[3]=f2bf_i(SCA[3]); \
    fr_[4]=f2bf_i(SCB[0]); fr_[5]=f2bf_i(SCB[1]); fr_[6]=f2bf_i(SCB[2]); fr_[7]=f2bf_i(SCB[3]); \
    _Pragma("unroll")                                                         \
    for (int nf_ = 0; nf_ < 16; ++nf_) {                                      \
      short8 bfr_ = *(const short8*)&lsB[(KC) & 1][nf_ * 512 + boff];         \
      acc[nf_] = __builtin_amdgcn_mfma_f32_16x16x32_bf16(fr_, bfr_, acc[nf_], 0, 0, 0); \
    }                                                                         \
    FENCE();                                                                  \
    __builtin_amdgcn_s_barrier();                                             \
    FENCE();                                                                  \
  }

// Kernel 1: fused GEMM(x@W)+tanh+dot(u) -> scores; per-block softmax partials
// (m, l) and context partial; the LAST block of each batch (device-scope
// atomic ticket) performs the batch combine + weights, overlapped with other
// batches' compute. grid NBLK, 256 thr (4 waves), 4 blocks/CU (R19/R21).
__global__ __launch_bounds__(256, 4)
void k_scores(const float* __restrict__ x, const short* __restrict__ wt,
              const float* __restrict__ bias, const float* __restrict__ u,
              float* __restrict__ ws_scores, float* __restrict__ ws_m,
              float* __restrict__ ws_l, float* __restrict__ ws_c,
              int* __restrict__ ws_cnt,
              float* __restrict__ out_ctx, float* __restrict__ out_w) {
  __shared__ __align__(16) short lsB[2][D_ * BK];   // 2 x 16 KB, frag-packed
  __shared__ __align__(8) float bu[D_ * 2];         // (bias, u) pairs
  __shared__ float score_lds[BM];
  __shared__ float e_lds[BM];
  __shared__ float red_lds[2];
  __shared__ int last_flag;

  const int tid  = threadIdx.x;
  const int bid  = blockIdx.x;
  const int m0   = bid * BM;
  const int lane = tid & 63;
  const int wv   = tid >> 6;       // 0..3 : 16-row group
  const int cl   = lane & 15;
  const int gr   = lane >> 4;      // 0..3
  const int boff = lane * 8;       // B-read: lane-linear 16B slots (no conflicts)

  bu[tid * 2]     = bias[tid];
  bu[tid * 2 + 1] = u[tid];

  f32x4 acc[16];
#pragma unroll
  for (int j = 0; j < 16; ++j) acc[j] = (f32x4){0.f, 0.f, 0.f, 0.f};

  const float* xrow = x + (size_t)(m0 + wv * 16 + cl) * D_ + gr * 8;

  // Prologue: queue = A(0)[2], stage(0)[4], A(1)[2]
  f4 s0a, s0b, s1a, s1b, s2a, s2b;
  s0a = *(const f4*)(xrow);       s0b = *(const f4*)(xrow + 4);
  STAGE(0, 0);
  s1a = *(const f4*)(xrow + 32);  s1b = *(const f4*)(xrow + 36);

  ITER(0, 8, s0a, s0b, s2a, s2b, 1, 1)
  ITER(1, 8, s1a, s1b, s0a, s0b, 1, 1)
  ITER(2, 8, s2a, s2b, s1a, s1b, 1, 1)
  ITER(3, 8, s0a, s0b, s2a, s2b, 1, 1)
  ITER(4, 8, s1a, s1b, s0a, s0b, 1, 1)
  ITER(5, 8, s2a, s2b, s1a, s1b, 1, 1)
  ITER(6, 6, s0a, s0b, s0a, s0b, 1, 0)
  ITER(7, 0, s1a, s1b, s0a, s0b, 0, 0)

  // Epilogue: score[row] = sum_n tanh(acc[row][n] + b[n]) * u[n]  (R21 verbatim)
  float p0 = 0.f, p1 = 0.f, p2 = 0.f, p3 = 0.f;
#pragma unroll
  for (int nf = 0; nf < 16; ++nf) {
    float bb = bu[(nf * 16 + cl) * 2];
    float uu = bu[(nf * 16 + cl) * 2 + 1];
    p0 += fast_tanh(acc[nf][0] + bb) * uu;
    p1 += fast_tanh(acc[nf][1] + bb) * uu;
    p2 += fast_tanh(acc[nf][2] + bb) * uu;
    p3 += fast_tanh(acc[nf][3] + bb) * uu;
  }
#pragma unroll
  for (int m = 1; m < 16; m <<= 1) {
    p0 += __shfl_xor(p0, m);
    p1 += __shfl_xor(p1, m);
    p2 += __shfl_xor(p2, m);
    p3 += __shfl_xor(p3, m);
  }
  if (cl == 0) {
    int r = wv * 16 + gr * 4;
    score_lds[r + 0] = p0;
    score_lds[r + 1] = p1;
    score_lds[r + 2] = p2;
    score_lds[r + 3] = p3;
    ws_scores[m0 + r + 0] = p0;
    ws_scores[m0 + r + 1] = p1;
    ws_scores[m0 + r + 2] = p2;
    ws_scores[m0 + r + 3] = p3;
  }
  __syncthreads();
  if (tid < 64) {
    float v = score_lds[tid];
#pragma unroll
    for (int m = 32; m >= 1; m >>= 1) v = fmaxf(v, __shfl_xor(v, m));
    if (tid == 0) red_lds[0] = v;
  }
  __syncthreads();
  float mb = red_lds[0];
  if (tid < BM) e_lds[tid] = __expf(score_lds[tid] - mb);
  __syncthreads();
  if (tid < 64) {
    float v = e_lds[tid];
#pragma unroll
    for (int m = 32; m >= 1; m >>= 1) v += __shfl_xor(v, m);
    if (tid == 0) { ws_m[bid] = mb; ws_l[bid] = v; }
  }
  // context partial: thread owns column d = tid; x tile is L1/L2-hot
  float cacc = 0.f;
  const float* xp = x + (size_t)m0 * D_ + tid;
#pragma unroll 4
  for (int s = 0; s < BM; ++s) cacc = fmaf(e_lds[s], xp[(size_t)s * D_], cacc);
  ws_c[bid * D_ + tid] = cacc;

  // ---- last-block-per-batch fused combine + weights -------------------------
  __threadfence();          // each thread flushes its own ws_* stores device-wide
  __syncthreads();          // all threads' fences complete
  const int b = bid >> 6;   // batch index (BLKS_PER_B = 64)
  if (tid == 0) {
    int t = atomicAdd(&ws_cnt[b], 1);
    last_flag = (t == BLKS_PER_B - 1);
  }
  __syncthreads();
  if (!last_flag) return;
  __threadfence();          // order our subsequent loads after the ticket

  // fac/M/L over the batch's 64 block partials (reuse score_lds as fac)
  if (tid < 64) {
    float m = ws_m[b * BLKS_PER_B + tid];
    float M = m;
#pragma unroll
    for (int o = 32; o >= 1; o >>= 1) M = fmaxf(M, __shfl_xor(M, o));
    float f = __expf(m - M);
    score_lds[tid] = f;
    float L = ws_l[b * BLKS_PER_B + tid] * f;
#pragma unroll
    for (int o = 32; o >= 1; o >>= 1) L += __shfl_xor(L, o);
    if (tid == 0) { red_lds[0] = M; red_lds[1] = L; }
  }
  __syncthreads();
  const float M = red_lds[0];
  const float invL = 1.0f / red_lds[1];

  // context out: thread owns column tid
  {
    float c = 0.f;
#pragma unroll 8
    for (int i = 0; i < BLKS_PER_B; ++i)
      c = fmaf(score_lds[i], ws_c[(size_t)(b * BLKS_PER_B + i) * D_ + tid], c);
    out_ctx[b * D_ + tid] = c * invL;
  }
  // weights: 16 per thread
#pragma unroll
  for (int r = 0; r < 16; ++r) {
    int s = r * 256 + tid;
    out_w[b * S_ + s] = __expf(ws_scores[b * S_ + s] - M) * invL;
  }
}

extern "C" void kernel_launch(void* const* d_in, const int* in_sizes, int n_in,
                              void* d_out, int out_size, void* d_ws, size_t ws_size,
                              hipStream_t stream) {
  (void)in_sizes; (void)n_in; (void)out_size; (void)ws_size;
  const float* x    = (const float*)d_in[0];
  const float* W    = (const float*)d_in[1];
  const float* bias = (const float*)d_in[2];
  const float* u    = (const float*)d_in[3];
  float* out_ctx = (float*)d_out;                 // [64,256]
  float* out_w   = (float*)d_out + B_ * D_;       // [64,4096]

  char* ws = (char*)d_ws;
  short* wt        = (short*)(ws + 0);            // 131072 B (frag-packed)
  float* ws_scores = (float*)(ws + 131072);       // 1048576 B
  float* ws_m      = (float*)(ws + 1179648);      // 16384 B
  float* ws_l      = (float*)(ws + 1196032);      // 16384 B
  float* ws_c      = (float*)(ws + 1212416);      // 4194304 B
  int*   ws_cnt    = (int*)(ws + 5406720);        // 256 B (64 counters)

  hipLaunchKernelGGL(k_pack, dim3(64), dim3(1024), 0, stream, W, wt, ws_cnt);
  hipLaunchKernelGGL(k_scores, dim3(NBLK), dim3(256), 0, stream,
                     x, wt, bias, u, ws_scores, ws_m, ws_l, ws_c,
                     ws_cnt, out_ctx, out_w);
}

// Round 23
// 106.183 us; speedup vs baseline: 7.0523x; 7.0523x over previous
//
#include <hip/hip_runtime.h>
#include <hip/hip_bf16.h>
#include <cstdint>
#include <cstddef>

// Problem constants
#define B_ 64
#define S_ 4096
#define D_ 256
#define BM 64                   // rows per block (4 waves x 16 rows)
#define BK 32                   // k-step
#define NBLK (B_ * S_ / BM)     // 4096
#define BLKS_PER_B (S_ / BM)    // 64

typedef __attribute__((ext_vector_type(8))) short short8;
typedef __attribute__((ext_vector_type(4))) float f32x4;
typedef __attribute__((ext_vector_type(4))) float f4;

__device__ __forceinline__ short f2bf(float f) {
  union { float f; uint32_t u; } v; v.f = f;
  uint32_t r = v.u + 0x7FFFu + ((v.u >> 16) & 1u);   // RNE
  return (short)(r >> 16);
}

__device__ __forceinline__ short f2bf_i(float f) {
  // compiler-visible RNE convert (no inline asm; R17/R18/R19/R21-proven)
  union { __hip_bfloat16 b; short s; } v;
  v.b = __float2bfloat16(f);
  return v.s;
}

__device__ __forceinline__ float fast_tanh(float z) {
  // tanh(z) = 1 - 2*rcp(e^{2z}+1); overflow-safe; rcp form PASSED R4/5/6/14/17/18/19/21
  return 1.0f - 2.0f * __builtin_amdgcn_rcpf(__expf(2.0f * z) + 1.0f);
}

__device__ __forceinline__ void gload_lds16(const short* g, short* l) {
  __builtin_amdgcn_global_load_lds(
      (const __attribute__((address_space(1))) int*)(g),
      (__attribute__((address_space(3))) int*)(l), 16, 0, 0);
}

// Kernel 0: FRAG-PACKED Wt (R18 layout). Output order: [kc][p][j] with
// p = nf*64+gr*16+cl, holding bf16(W[k][n]) for n = nf*16+cl, k = kc*32+gr*8+j.
// => stage source linear in tid; LDS B-read lane-linear 1KB (conflict-free).
__global__ void k_pack(const float* __restrict__ W, short* __restrict__ wt) {
  int idx = blockIdx.x * 1024 + threadIdx.x;   // 65536 elements
  int n = idx & 255, k = idx >> 8;             // coalesced read of row k
  int out = (k >> 5) * 8192 +
            (((n >> 4) * 64 + ((k >> 3) & 3) * 16 + (n & 15)) << 3) + (k & 7);
  wt[out] = f2bf(W[k * 256 + n]);
}

// ---- k_scores helper macros (R19/R21-proven pipeline) -----------------------
#define WAITV(N) asm volatile("s_waitcnt vmcnt(" #N ")" ::: "memory")
#define FENCE()  asm volatile("" ::: "memory")

// Stage B k-step KC into lsB[BUF]: 16 KB, 4 x global_load_lds(16B) per thread.
// Source is LINEAR (frag-packed wt) -> fully coalesced 16KB burst from L2.
#define STAGE(BUF, KC)                                                        \
  {                                                                           \
    _Pragma("unroll")                                                         \
    for (int i_ = 0; i_ < 4; ++i_) {                                          \
      int c_ = i_ * 256 + tid;                                                \
      gload_lds16(wt + (KC) * 8192 + c_ * 8, &lsB[BUF][c_ * 8]);              \
    }                                                                         \
  }

// One pipelined K-step (R21 verbatim): stage(K+1), issue A(K+2), counted
// vmcnt, barriers, cvt A(K), 16 MFMAs (lane-linear conflict-free B reads).
#define ITER(KC, VM, SCA, SCB, SLA, SLB, DOSTAGE, DOLOAD)                     \
  {                                                                           \
    if (DOSTAGE) STAGE(((KC) + 1) & 1, (KC) + 1);                             \
    if (DOLOAD) {                                                             \
      SLA = *(const f4*)(xrow + ((KC) + 2) * 32);                             \
      SLB = *(const f4*)(xrow + ((KC) + 2) * 32 + 4);                         \
    }                                                                         \
    WAITV(VM);                                                                \
    asm volatile("s_waitcnt lgkmcnt(0)" ::: "memory");                        \
    __builtin_amdgcn_sched_barrier(0);                                        \
    __builtin_amdgcn_s_barrier();                                             \
    FENCE();                                                                  \
    short8 fr_;                                                               \
    fr_[0]=f2bf_i(SCA[0]); fr_[1]=f2bf_i(SCA[1]); fr_[2]=f2bf_i(SCA[2]); fr_[3]=f2bf_i(SCA[3]); \
    fr_[4]=f2bf_i(SCB[0]); fr_[5]=f2bf_i(SCB[1]); fr_[6]=f2bf_i(SCB[2]); fr_[7]=f2bf_i(SCB[3]); \
    _Pragma("unroll")                                                         \
    for (int nf_ = 0; nf_ < 16; ++nf_) {                                      \
      short8 bfr_ = *(const short8*)&lsB[(KC) & 1][nf_ * 512 + boff];         \
      acc[nf_] = __builtin_amdgcn_mfma_f32_16x16x32_bf16(fr_, bfr_, acc[nf_], 0, 0, 0); \
    }                                                                         \
    FENCE();                                                                  \
    __builtin_amdgcn_s_barrier();                                             \
    FENCE();                                                                  \
  }

// Kernel 1: fused GEMM(x@W)+tanh+dot(u) -> scores; per-block softmax partials
// (m, l) and context partial. grid NBLK, 256 thr (4 waves, 16 rows each).
// __launch_bounds__(256,4): 4 resident blocks/CU (128 unified regs exactly;
// LDS 35.8KB x 4 < 160KB) — R19/R21-proven, the occupancy cap for this family.
__global__ __launch_bounds__(256, 4)
void k_scores(const float* __restrict__ x, const short* __restrict__ wt,
              const float* __restrict__ bias, const float* __restrict__ u,
              float* __restrict__ ws_scores, float* __restrict__ ws_m,
              float* __restrict__ ws_l, float* __restrict__ ws_c) {
  __shared__ __align__(16) short lsB[2][D_ * BK];   // 2 x 16 KB, frag-packed
  __shared__ __align__(8) float bu[D_ * 2];         // (bias, u) pairs
  __shared__ float score_lds[BM];
  __shared__ float e_lds[BM];
  __shared__ float red_lds[1];

  const int tid  = threadIdx.x;
  const int bid  = blockIdx.x;
  const int m0   = bid * BM;
  const int lane = tid & 63;
  const int wv   = tid >> 6;       // 0..3 : 16-row group
  const int cl   = lane & 15;
  const int gr   = lane >> 4;      // 0..3
  const int boff = lane * 8;       // B-read: lane-linear 16B slots (no conflicts)

  // (bias,u) first: compiler drains their loads before the ds_write, keeping
  // the vmcnt queue empty when the pipelined loads start.  (R21 verbatim)
  bu[tid * 2]     = bias[tid];
  bu[tid * 2 + 1] = u[tid];

  f32x4 acc[16];
#pragma unroll
  for (int j = 0; j < 16; ++j) acc[j] = (f32x4){0.f, 0.f, 0.f, 0.f};

  const float* xrow = x + (size_t)(m0 + wv * 16 + cl) * D_ + gr * 8;

  // Prologue: queue = A(0)[2], stage(0)[4], A(1)[2]
  f4 s0a, s0b, s1a, s1b, s2a, s2b;
  s0a = *(const f4*)(xrow);       s0b = *(const f4*)(xrow + 4);
  STAGE(0, 0);
  s1a = *(const f4*)(xrow + 32);  s1b = *(const f4*)(xrow + 36);

  // Steady state: 8 outstanding (4 stage + 2+2 A) stay in flight across waits.
  ITER(0, 8, s0a, s0b, s2a, s2b, 1, 1)
  ITER(1, 8, s1a, s1b, s0a, s0b, 1, 1)
  ITER(2, 8, s2a, s2b, s1a, s1b, 1, 1)
  ITER(3, 8, s0a, s0b, s2a, s2b, 1, 1)
  ITER(4, 8, s1a, s1b, s0a, s0b, 1, 1)
  ITER(5, 8, s2a, s2b, s1a, s1b, 1, 1)
  ITER(6, 6, s0a, s0b, s0a, s0b, 1, 0)
  ITER(7, 0, s1a, s1b, s0a, s0b, 0, 0)

  // Epilogue: score[row] = sum_n tanh(acc[row][n] + b[n]) * u[n]  (R21 verbatim)
  float p0 = 0.f, p1 = 0.f, p2 = 0.f, p3 = 0.f;
#pragma unroll
  for (int nf = 0; nf < 16; ++nf) {
    float bb = bu[(nf * 16 + cl) * 2];
    float uu = bu[(nf * 16 + cl) * 2 + 1];
    p0 += fast_tanh(acc[nf][0] + bb) * uu;
    p1 += fast_tanh(acc[nf][1] + bb) * uu;
    p2 += fast_tanh(acc[nf][2] + bb) * uu;
    p3 += fast_tanh(acc[nf][3] + bb) * uu;
  }
#pragma unroll
  for (int m = 1; m < 16; m <<= 1) {
    p0 += __shfl_xor(p0, m);
    p1 += __shfl_xor(p1, m);
    p2 += __shfl_xor(p2, m);
    p3 += __shfl_xor(p3, m);
  }
  if (cl == 0) {
    int r = wv * 16 + gr * 4;
    score_lds[r + 0] = p0;
    score_lds[r + 1] = p1;
    score_lds[r + 2] = p2;
    score_lds[r + 3] = p3;
    ws_scores[m0 + r + 0] = p0;
    ws_scores[m0 + r + 1] = p1;
    ws_scores[m0 + r + 2] = p2;
    ws_scores[m0 + r + 3] = p3;
  }
  __syncthreads();
  // block max over 64 scores (wave 0)
  if (tid < 64) {
    float v = score_lds[tid];
#pragma unroll
    for (int m = 32; m >= 1; m >>= 1) v = fmaxf(v, __shfl_xor(v, m));
    if (tid == 0) red_lds[0] = v;
  }
  __syncthreads();
  float mb = red_lds[0];
  if (tid < BM) e_lds[tid] = __expf(score_lds[tid] - mb);
  __syncthreads();
  if (tid < 64) {
    float v = e_lds[tid];
#pragma unroll
    for (int m = 32; m >= 1; m >>= 1) v += __shfl_xor(v, m);
    if (tid == 0) { ws_m[bid] = mb; ws_l[bid] = v; }
  }
  // context partial: thread owns column d = tid; x tile is L1/L2-hot
  float cacc = 0.f;
  const float* xp = x + (size_t)m0 * D_ + tid;
#pragma unroll 4
  for (int s = 0; s < BM; ++s) cacc = fmaf(e_lds[s], xp[(size_t)s * D_], cacc);
  ws_c[bid * D_ + tid] = cacc;
}

// Kernel 2 (fused combine+weights): grid B_ (64), 1024 thr.  (R21 verbatim)
__global__ __launch_bounds__(1024)
void k_epi(const float* __restrict__ ws_m, const float* __restrict__ ws_l,
           const float* __restrict__ ws_c, const float* __restrict__ ws_scores,
           float* __restrict__ out_ctx, float* __restrict__ out_w) {
  __shared__ float fac[BLKS_PER_B];
  __shared__ float MLs[2];
  const int b = blockIdx.x, tid = threadIdx.x;

  if (tid < 64) {
    float m = ws_m[b * BLKS_PER_B + tid];
    float l = ws_l[b * BLKS_PER_B + tid];
    float M = m;
#pragma unroll
    for (int o = 32; o >= 1; o >>= 1) M = fmaxf(M, __shfl_xor(M, o));
    float f = __expf(m - M);
    fac[tid] = f;
    float L = l * f;
#pragma unroll
    for (int o = 32; o >= 1; o >>= 1) L += __shfl_xor(L, o);
    if (tid == 0) { MLs[0] = M; MLs[1] = L; }
  }
  __syncthreads();
  const float M = MLs[0], L = MLs[1];
  const float invL = 1.0f / L;

  if (tid < D_) {
    float c = 0.f;
#pragma unroll 8
    for (int i = 0; i < BLKS_PER_B; ++i)
      c = fmaf(fac[i], ws_c[(size_t)(b * BLKS_PER_B + i) * D_ + tid], c);
    out_ctx[b * D_ + tid] = c * invL;
  }
#pragma unroll
  for (int r = 0; r < 4; ++r) {
    int s = r * 1024 + tid;
    out_w[b * S_ + s] = __expf(ws_scores[b * S_ + s] - M) * invL;
  }
}

extern "C" void kernel_launch(void* const* d_in, const int* in_sizes, int n_in,
                              void* d_out, int out_size, void* d_ws, size_t ws_size,
                              hipStream_t stream) {
  (void)in_sizes; (void)n_in; (void)out_size; (void)ws_size;
  const float* x    = (const float*)d_in[0];
  const float* W    = (const float*)d_in[1];
  const float* bias = (const float*)d_in[2];
  const float* u    = (const float*)d_in[3];
  float* out_ctx = (float*)d_out;                 // [64,256]
  float* out_w   = (float*)d_out + B_ * D_;       // [64,4096]

  char* ws = (char*)d_ws;
  short* wt        = (short*)(ws + 0);            // 131072 B (frag-packed)
  float* ws_scores = (float*)(ws + 131072);       // 1048576 B
  float* ws_m      = (float*)(ws + 1179648);      // 16384 B
  float* ws_l      = (float*)(ws + 1196032);      // 16384 B
  float* ws_c      = (float*)(ws + 1212416);      // 4194304 B

  hipLaunchKernelGGL(k_pack, dim3(64), dim3(1024), 0, stream, W, wt);
  hipLaunchKernelGGL(k_scores, dim3(NBLK), dim3(256), 0, stream,
                     x, wt, bias, u, ws_scores, ws_m, ws_l, ws_c);
  hipLaunchKernelGGL(k_epi, dim3(B_), dim3(1024), 0, stream,
                     ws_m, ws_l, ws_c, ws_scores, out_ctx, out_w);
}